// Round 1
// baseline (986.378 us; speedup 1.0000x reference)
//
#include <hip/hip_runtime.h>
#include <math.h>

#define DIM 384
#define NUM_HEADS 8
#define RES 14
#define RES2 7
#define NPOS 196
#define N2 49
#define DHEAD 64
#define NH_KD 128
#define DH 512
#define OUT_DIM 768
#define BATCH 512
#define SCALE_Q 0.25f

typedef unsigned short u16;
typedef short s16x8 __attribute__((ext_vector_type(8)));
typedef float f32x4 __attribute__((ext_vector_type(4)));

__device__ __forceinline__ float bf2f(u16 u) {
  union { unsigned int i; float f; } v; v.i = ((unsigned int)u) << 16; return v.f;
}
__device__ __forceinline__ u16 f2bf(float f) {
  union { unsigned int i; float f; } v; v.f = f;
  unsigned int r = v.i + 0x7fffu + ((v.i >> 16) & 1u);
  return (u16)(r >> 16);
}

// ---------- small prep kernels ----------
__global__ __launch_bounds__(256) void k_f2bf(const float* __restrict__ s, u16* __restrict__ d, int n) {
  int i = blockIdx.x * 256 + threadIdx.x;
  if (i < n) d[i] = f2bf(s[i]);
}

__global__ __launch_bounds__(256) void k_biasx(const float* __restrict__ ab, const int* __restrict__ idxs,
                                               float* __restrict__ bx, int noff) {
  int i = blockIdx.x * 256 + threadIdx.x;
  if (i < NUM_HEADS * N2 * NPOS) {
    int h = i / (N2 * NPOS), r = i % (N2 * NPOS);
    bx[i] = ab[h * noff + idxs[r]];
  }
}

// ---------- x (f32 [b][384][196]) -> xbT (bf16 [b][196][384]) ----------
__global__ __launch_bounds__(256) void k_transpose(const float* __restrict__ x, u16* __restrict__ xt) {
  int b = blockIdx.y, c0 = blockIdx.x * 64;
  __shared__ u16 tile[64][196];
  int tid = threadIdx.x, wave = tid >> 6, lane = tid & 63;
  const float* xb = x + (size_t)b * DIM * NPOS;
  for (int r = wave; r < 64; r += 4) {
    const float* row = xb + (size_t)(c0 + r) * NPOS;
    tile[r][lane]       = f2bf(row[lane]);
    tile[r][lane + 64]  = f2bf(row[lane + 64]);
    tile[r][lane + 128] = f2bf(row[lane + 128]);
    if (lane < 4) tile[r][lane + 192] = f2bf(row[lane + 192]);
  }
  __syncthreads();
  u16* xtb = xt + (size_t)b * NPOS * DIM;
  for (int n = wave; n < NPOS; n += 4)
    xtb[(size_t)n * DIM + c0 + lane] = tile[lane][n];
}

// ---------- ql = dwconv_s2(x) + b + x[::2,::2]  -> qlT (bf16 [b][49][384]) ----------
__global__ __launch_bounds__(256) void k_dwconv_q(const u16* __restrict__ xt, const float* __restrict__ w,
                                                  const float* __restrict__ bias, u16* __restrict__ qlt) {
  int b = blockIdx.y;
  int lid = blockIdx.x * 256 + threadIdx.x;
  if (lid >= N2 * DIM) return;
  int n2 = lid / DIM, c = lid % DIM;
  int r = n2 / RES2, s = n2 % RES2;
  const u16* xb = xt + (size_t)b * NPOS * DIM;
  float acc = bias[c];
#pragma unroll
  for (int dy = 0; dy < 3; dy++) {
    int ry = 2 * r - 1 + dy;
    if (ry < 0 || ry >= RES) continue;
#pragma unroll
    for (int dx = 0; dx < 3; dx++) {
      int sx = 2 * s - 1 + dx;
      if (sx < 0 || sx >= RES) continue;
      acc += w[c * 9 + dy * 3 + dx] * bf2f(xb[(size_t)(ry * RES + sx) * DIM + c]);
    }
  }
  acc += bf2f(xb[(size_t)(2 * r * RES + 2 * s) * DIM + c]);  // strided residual
  qlt[((size_t)b * N2 + n2) * DIM + c] = f2bf(acc);
}

// ---------- generic  C[b][m][n] = (sum_k Arow[m][k]*Brow[n][k]) * s[ch] + (cb[ch]*s[ch]+t[ch]) ----------
// A rows: stride K, clamped to Marows. B rows: stride K, staged only for rb<Brows (cols beyond -> garbage, never stored).
template <int NFRAG, bool CHAN_M, bool F32OUT>
__global__ __launch_bounds__(256) void k_gemm_bt(
    const u16* __restrict__ A, const u16* __restrict__ B, void* __restrict__ C,
    const float* __restrict__ cb, const float* __restrict__ bns, const float* __restrict__ bnt,
    long sAb, long sBb, long sCb, int K, int Marows, int Brows, int Mstore, int Nstore, int ldc) {
  int b = blockIdx.y, m0 = blockIdx.x * 64;
  const u16* Ab = A + (size_t)b * sAb;
  const u16* Bb = B + (size_t)b * sBb;
  __shared__ __align__(16) u16 a_lds[64 * 32];
  __shared__ __align__(16) u16 b_lds[NFRAG * 16 * 32];
  int tid = threadIdx.x, wave = tid >> 6, lane = tid & 63;
  f32x4 acc[NFRAG];
#pragma unroll
  for (int f = 0; f < NFRAG; f++) acc[f] = (f32x4){0.f, 0.f, 0.f, 0.f};

  int arow_l = wave * 16 + (lane >> 2);
  int akoff = (lane & 3) * 8;
  int arow_g = m0 + arow_l; if (arow_g > Marows - 1) arow_g = Marows - 1;
  int brow0 = tid >> 2, bkoff = (tid & 3) * 8;
  int a_rd = (wave * 16 + (lane & 15)) * 32 + (lane >> 4) * 8;

  for (int kk = 0; kk < K; kk += 32) {
    *(s16x8*)(&a_lds[arow_l * 32 + akoff]) = *(const s16x8*)(Ab + (size_t)arow_g * K + kk + akoff);
#pragma unroll
    for (int i = 0; i < (NFRAG + 3) / 4; i++) {
      int rb = i * 64 + brow0;
      if (rb < Brows)
        *(s16x8*)(&b_lds[rb * 32 + bkoff]) = *(const s16x8*)(Bb + (size_t)rb * K + kk + bkoff);
    }
    __syncthreads();
    s16x8 af = *(const s16x8*)(&a_lds[a_rd]);
#pragma unroll
    for (int f = 0; f < NFRAG; f++) {
      s16x8 bf = *(const s16x8*)(&b_lds[(f * 16 + (lane & 15)) * 32 + (lane >> 4) * 8]);
      acc[f] = __builtin_amdgcn_mfma_f32_16x16x32_bf16(af, bf, acc[f], 0, 0, 0);
    }
    __syncthreads();
  }
  int mbase = m0 + wave * 16 + (lane >> 4) * 4;
  int ncol0 = lane & 15;
#pragma unroll
  for (int f = 0; f < NFRAG; f++) {
    int n = f * 16 + ncol0;
#pragma unroll
    for (int r = 0; r < 4; r++) {
      int m = mbase + r;
      if (m < Mstore && n < Nstore) {
        int ch = CHAN_M ? m : n;
        float val = acc[f][r] * bns[ch] + (cb[ch] * bns[ch] + bnt[ch]);
        size_t o = (size_t)b * sCb + (size_t)m * ldc + n;
        if (F32OUT) ((float*)C)[o] = val;
        else ((u16*)C)[o] = f2bf(val);
      }
    }
  }
}

// ---------- v_local = BN(dwconv_s2(v4) + b) -> vlT (bf16 [b][49][512]) ----------
__global__ __launch_bounds__(256) void k_dwconv_v(const u16* __restrict__ v4, const float* __restrict__ w,
    const float* __restrict__ bias, const float* __restrict__ bns, const float* __restrict__ bnt,
    u16* __restrict__ vlt) {
  int b = blockIdx.y, ct = blockIdx.x;
  __shared__ u16 tile[64][196];
  int tid = threadIdx.x, wave = tid >> 6, lane = tid & 63;
  const u16* vbp = v4 + ((size_t)b * DH + ct * 64) * NPOS;
  for (int r = wave; r < 64; r += 4) {
    const u16* row = vbp + (size_t)r * NPOS;
    tile[r][lane]       = row[lane];
    tile[r][lane + 64]  = row[lane + 64];
    tile[r][lane + 128] = row[lane + 128];
    if (lane < 4) tile[r][lane + 192] = row[lane + 192];
  }
  __syncthreads();
  for (int idx = tid; idx < 64 * N2; idx += 256) {
    int cl = idx & 63, n2 = idx >> 6;
    int ch = ct * 64 + cl;
    int r = n2 / RES2, s = n2 % RES2;
    float acc = bias[ch];
#pragma unroll
    for (int dy = 0; dy < 3; dy++) {
      int ry = 2 * r - 1 + dy;
      if (ry < 0 || ry >= RES) continue;
#pragma unroll
      for (int dx = 0; dx < 3; dx++) {
        int sx = 2 * s - 1 + dx;
        if (sx < 0 || sx >= RES) continue;
        acc += w[ch * 9 + dy * 3 + dx] * bf2f(tile[cl][ry * RES + sx]);
      }
    }
    vlt[((size_t)b * N2 + n2) * DH + ch] = f2bf(acc * bns[ch] + bnt[ch]);
  }
}

// ---------- attention per (b,h): S=qk*scale+bias, softmax, PV; += v_local; gelu -> gT (bf16 [b][49][512]) ----------
__global__ __launch_bounds__(256) void k_attn(const u16* __restrict__ qT, const u16* __restrict__ kT,
    const u16* __restrict__ v4, const float* __restrict__ biasx, const u16* __restrict__ vlT,
    u16* __restrict__ gT) {
  int h = blockIdx.x, b = blockIdx.y;
  __shared__ float S[N2][196];
  __shared__ u16 vl[196][66];
  int tid = threadIdx.x, wave = tid >> 6, lane = tid & 63;
  const u16* vbp = v4 + ((size_t)b * DH + h * DHEAD) * NPOS;
  for (int d = 0; d < DHEAD; d++)
    if (tid < NPOS) vl[tid][d] = vbp[(size_t)d * NPOS + tid];
  if (tid < NPOS) {
    int n = tid;
    float kreg[16];
    const u16* kp = kT + ((size_t)b * NPOS + n) * NH_KD + h * 16;
#pragma unroll
    for (int c = 0; c < 16; c++) kreg[c] = bf2f(kp[c]);
    const u16* qp = qT + (size_t)b * N2 * NH_KD + h * 16;
    const float* bxp = biasx + (size_t)h * N2 * NPOS;
    for (int n2 = 0; n2 < N2; n2++) {
      float acc = 0.f;
#pragma unroll
      for (int c = 0; c < 16; c++) acc += kreg[c] * bf2f(qp[n2 * NH_KD + c]);
      S[n2][n] = acc * SCALE_Q + bxp[n2 * NPOS + n];
    }
  }
  __syncthreads();
  for (int row = wave; row < N2; row += 4) {
    float v0 = S[row][lane], v1 = S[row][lane + 64], v2 = S[row][lane + 128];
    float v3 = (lane < 4) ? S[row][lane + 192] : -1e30f;
    float m = fmaxf(fmaxf(v0, v1), fmaxf(v2, v3));
#pragma unroll
    for (int off = 32; off > 0; off >>= 1) m = fmaxf(m, __shfl_xor(m, off));
    float e0 = expf(v0 - m), e1 = expf(v1 - m), e2 = expf(v2 - m);
    float e3 = (lane < 4) ? expf(v3 - m) : 0.f;
    float sum = e0 + e1 + e2 + e3;
#pragma unroll
    for (int off = 32; off > 0; off >>= 1) sum += __shfl_xor(sum, off);
    float inv = 1.f / sum;
    S[row][lane] = e0 * inv; S[row][lane + 64] = e1 * inv; S[row][lane + 128] = e2 * inv;
    if (lane < 4) S[row][lane + 192] = e3 * inv;
  }
  __syncthreads();
  int d = tid & 63;
  for (int n2 = tid >> 6; n2 < N2; n2 += 4) {
    float acc = 0.f;
    for (int n = 0; n < NPOS; n++) acc += S[n2][n] * bf2f(vl[n][d]);
    size_t o = ((size_t)b * N2 + n2) * DH + h * DHEAD + d;
    float xv = acc + bf2f(vlT[o]);
    float g = 0.5f * xv * (1.f + erff(xv * 0.70710678118f));
    gT[o] = f2bf(g);
  }
}

extern "C" void kernel_launch(void* const* d_in, const int* in_sizes, int n_in,
                              void* d_out, int out_size, void* d_ws, size_t ws_size,
                              hipStream_t stream) {
  const float* x   = (const float*)d_in[0];
  const float* qlw = (const float*)d_in[1];
  const float* qlb = (const float*)d_in[2];
  const float* qpw = (const float*)d_in[3];
  const float* qpb = (const float*)d_in[4];
  const float* qbs = (const float*)d_in[5];
  const float* qbt = (const float*)d_in[6];
  const float* kw  = (const float*)d_in[7];
  const float* kb  = (const float*)d_in[8];
  const float* kbs = (const float*)d_in[9];
  const float* kbt = (const float*)d_in[10];
  const float* vw  = (const float*)d_in[11];
  const float* vb  = (const float*)d_in[12];
  const float* vbs = (const float*)d_in[13];
  const float* vbt = (const float*)d_in[14];
  const float* vlw = (const float*)d_in[15];
  const float* vlb = (const float*)d_in[16];
  const float* vls = (const float*)d_in[17];
  const float* vlt_in = (const float*)d_in[18];
  const float* pw  = (const float*)d_in[19];
  const float* pb  = (const float*)d_in[20];
  const float* pbs = (const float*)d_in[21];
  const float* pbt = (const float*)d_in[22];
  const float* ab  = (const float*)d_in[23];
  const int*   bidx = (const int*)d_in[24];
  int noff = in_sizes[23] / NUM_HEADS;

  char* ws = (char*)d_ws;
  size_t off = 0;
  auto alloc = [&](size_t bytes) { char* p = ws + off; off += (bytes + 255) & ~(size_t)255; return p; };
  u16* xbT = (u16*)alloc((size_t)BATCH * NPOS * DIM * 2);      // 77.1 MB (aliased by gT later)
  u16* kTm = (u16*)alloc((size_t)BATCH * NPOS * NH_KD * 2);    // 25.7 MB
  u16* qlT = (u16*)alloc((size_t)BATCH * N2 * DIM * 2);        // 19.3 MB
  u16* qTm = (u16*)alloc((size_t)BATCH * N2 * NH_KD * 2);      //  6.4 MB
  u16* v4m = (u16*)alloc((size_t)BATCH * DH * NPOS * 2);       // 102.8 MB
  u16* vlTm = (u16*)alloc((size_t)BATCH * N2 * DH * 2);        // 25.7 MB
  float* bx = (float*)alloc((size_t)NUM_HEADS * N2 * NPOS * 4);
  u16* kwb = (u16*)alloc((size_t)NH_KD * DIM * 2);
  u16* vwb = (u16*)alloc((size_t)DH * DIM * 2);
  u16* qwb = (u16*)alloc((size_t)NH_KD * DIM * 2);
  u16* pwb = (u16*)alloc((size_t)OUT_DIM * DH * 2);
  u16* gTm = xbT;  // alias: all xbT readers complete before k_attn writes gT

  k_f2bf<<<(NH_KD * DIM + 255) / 256, 256, 0, stream>>>(kw, kwb, NH_KD * DIM);
  k_f2bf<<<(DH * DIM + 255) / 256, 256, 0, stream>>>(vw, vwb, DH * DIM);
  k_f2bf<<<(NH_KD * DIM + 255) / 256, 256, 0, stream>>>(qpw, qwb, NH_KD * DIM);
  k_f2bf<<<(OUT_DIM * DH + 255) / 256, 256, 0, stream>>>(pw, pwb, OUT_DIM * DH);
  k_biasx<<<(NUM_HEADS * N2 * NPOS + 255) / 256, 256, 0, stream>>>(ab, bidx, bx, noff);

  k_transpose<<<dim3(6, BATCH), 256, 0, stream>>>(x, xbT);
  k_dwconv_q<<<dim3((N2 * DIM + 255) / 256, BATCH), 256, 0, stream>>>(xbT, qlw, qlb, qlT);

  // k: C[b][n][o]  (m = n_spatial, ch = col)
  k_gemm_bt<8, false, false><<<dim3(4, BATCH), 256, 0, stream>>>(
      xbT, kwb, kTm, kb, kbs, kbt,
      (long)NPOS * DIM, 0, (long)NPOS * NH_KD, DIM, NPOS, NH_KD, NPOS, NH_KD, NH_KD);
  // v: C[b][o][n]  (m = channel)
  k_gemm_bt<13, true, false><<<dim3(8, BATCH), 256, 0, stream>>>(
      vwb, xbT, v4m, vb, vbs, vbt,
      0, (long)NPOS * DIM, (long)DH * NPOS, DIM, DH, NPOS, DH, NPOS, NPOS);
  // q: C[b][n2][o]
  k_gemm_bt<8, false, false><<<dim3(1, BATCH), 256, 0, stream>>>(
      qlT, qwb, qTm, qpb, qbs, qbt,
      (long)N2 * DIM, 0, (long)N2 * NH_KD, DIM, N2, NH_KD, N2, NH_KD, NH_KD);

  k_dwconv_v<<<dim3(8, BATCH), 256, 0, stream>>>(v4m, vlw, vlb, vls, vlt_in, vlTm);
  k_attn<<<dim3(NUM_HEADS, BATCH), 256, 0, stream>>>(qTm, kTm, v4m, bx, vlTm, gTm);

  // p: C[b][o][n2] -> d_out f32
  k_gemm_bt<4, true, true><<<dim3(12, BATCH), 256, 0, stream>>>(
      pwb, gTm, d_out, pb, pbs, pbt,
      0, (long)N2 * DH, (long)OUT_DIM * N2, DH, OUT_DIM, N2, OUT_DIM, N2, N2);
}

// Round 2
// 793.204 us; speedup vs baseline: 1.2435x; 1.2435x over previous
//
#include <hip/hip_runtime.h>
#include <math.h>

#define DIM 384
#define NUM_HEADS 8
#define RES 14
#define RES2 7
#define NPOS 196
#define N2 49
#define DHEAD 64
#define NH_KD 128
#define DH 512
#define OUT_DIM 768
#define BATCH 512
#define SCALE_Q 0.25f

typedef unsigned short u16;
typedef short s16x8 __attribute__((ext_vector_type(8)));
typedef float f32x4 __attribute__((ext_vector_type(4)));

__device__ __forceinline__ float bf2f(u16 u) {
  union { unsigned int i; float f; } v; v.i = ((unsigned int)u) << 16; return v.f;
}
__device__ __forceinline__ u16 f2bf(float f) {
  union { unsigned int i; float f; } v; v.f = f;
  unsigned int r = v.i + 0x7fffu + ((v.i >> 16) & 1u);
  return (u16)(r >> 16);
}

// ---------- small prep kernels ----------
__global__ __launch_bounds__(256) void k_f2bf(const float* __restrict__ s, u16* __restrict__ d, int n) {
  int i = blockIdx.x * 256 + threadIdx.x;
  if (i < n) d[i] = f2bf(s[i]);
}

__global__ __launch_bounds__(256) void k_biasx(const float* __restrict__ ab, const int* __restrict__ idxs,
                                               float* __restrict__ bx, int noff) {
  int i = blockIdx.x * 256 + threadIdx.x;
  if (i < NUM_HEADS * N2 * NPOS) {
    int h = i / (N2 * NPOS), r = i % (N2 * NPOS);
    bx[i] = ab[h * noff + idxs[r]];
  }
}

// ---------- x (f32 [b][384][196]) -> xbT (bf16 [b][196][384]) ----------
__global__ __launch_bounds__(256) void k_transpose(const float* __restrict__ x, u16* __restrict__ xt) {
  int b = blockIdx.y, c0 = blockIdx.x * 64;
  __shared__ u16 tile[64][196];
  int tid = threadIdx.x, wave = tid >> 6, lane = tid & 63;
  const float* xb = x + (size_t)b * DIM * NPOS;
  for (int r = wave; r < 64; r += 4) {
    const float* row = xb + (size_t)(c0 + r) * NPOS;
    tile[r][lane]       = f2bf(row[lane]);
    tile[r][lane + 64]  = f2bf(row[lane + 64]);
    tile[r][lane + 128] = f2bf(row[lane + 128]);
    if (lane < 4) tile[r][lane + 192] = f2bf(row[lane + 192]);
  }
  __syncthreads();
  u16* xtb = xt + (size_t)b * NPOS * DIM;
  for (int n = wave; n < NPOS; n += 4)
    xtb[(size_t)n * DIM + c0 + lane] = tile[lane][n];
}

// ---------- ql = dwconv_s2(x) + b + x[::2,::2]  -> qlT (bf16 [b][49][384]) ----------
__global__ __launch_bounds__(256) void k_dwconv_q(const u16* __restrict__ xt, const float* __restrict__ w,
                                                  const float* __restrict__ bias, u16* __restrict__ qlt) {
  int b = blockIdx.y;
  int lid = blockIdx.x * 256 + threadIdx.x;
  if (lid >= N2 * DIM) return;
  int n2 = lid / DIM, c = lid % DIM;
  int r = n2 / RES2, s = n2 % RES2;
  const u16* xb = xt + (size_t)b * NPOS * DIM;
  float acc = bias[c];
#pragma unroll
  for (int dy = 0; dy < 3; dy++) {
    int ry = 2 * r - 1 + dy;
    if (ry < 0 || ry >= RES) continue;
#pragma unroll
    for (int dx = 0; dx < 3; dx++) {
      int sx = 2 * s - 1 + dx;
      if (sx < 0 || sx >= RES) continue;
      acc += w[c * 9 + dy * 3 + dx] * bf2f(xb[(size_t)(ry * RES + sx) * DIM + c]);
    }
  }
  acc += bf2f(xb[(size_t)(2 * r * RES + 2 * s) * DIM + c]);  // strided residual
  qlt[((size_t)b * N2 + n2) * DIM + c] = f2bf(acc);
}

// ---------- generic  C[b][m][n] = (sum_k Arow[m][k]*Brow[n][k]) * s[ch] + (cb[ch]*s[ch]+t[ch]) ----------
template <int NFRAG, bool CHAN_M, bool F32OUT>
__global__ __launch_bounds__(256) void k_gemm_bt(
    const u16* __restrict__ A, const u16* __restrict__ B, void* __restrict__ C,
    const float* __restrict__ cb, const float* __restrict__ bns, const float* __restrict__ bnt,
    long sAb, long sBb, long sCb, int K, int Marows, int Brows, int Mstore, int Nstore, int ldc) {
  int b = blockIdx.y, m0 = blockIdx.x * 64;
  const u16* Ab = A + (size_t)b * sAb;
  const u16* Bb = B + (size_t)b * sBb;
  __shared__ __align__(16) u16 a_lds[64 * 32];
  __shared__ __align__(16) u16 b_lds[NFRAG * 16 * 32];
  int tid = threadIdx.x, wave = tid >> 6, lane = tid & 63;
  f32x4 acc[NFRAG];
#pragma unroll
  for (int f = 0; f < NFRAG; f++) acc[f] = (f32x4){0.f, 0.f, 0.f, 0.f};

  int arow_l = wave * 16 + (lane >> 2);
  int akoff = (lane & 3) * 8;
  int arow_g = m0 + arow_l; if (arow_g > Marows - 1) arow_g = Marows - 1;
  int brow0 = tid >> 2, bkoff = (tid & 3) * 8;
  int a_rd = (wave * 16 + (lane & 15)) * 32 + (lane >> 4) * 8;

  for (int kk = 0; kk < K; kk += 32) {
    *(s16x8*)(&a_lds[arow_l * 32 + akoff]) = *(const s16x8*)(Ab + (size_t)arow_g * K + kk + akoff);
#pragma unroll
    for (int i = 0; i < (NFRAG + 3) / 4; i++) {
      int rb = i * 64 + brow0;
      if (rb < Brows)
        *(s16x8*)(&b_lds[rb * 32 + bkoff]) = *(const s16x8*)(Bb + (size_t)rb * K + kk + bkoff);
    }
    __syncthreads();
    s16x8 af = *(const s16x8*)(&a_lds[a_rd]);
#pragma unroll
    for (int f = 0; f < NFRAG; f++) {
      s16x8 bf = *(const s16x8*)(&b_lds[(f * 16 + (lane & 15)) * 32 + (lane >> 4) * 8]);
      acc[f] = __builtin_amdgcn_mfma_f32_16x16x32_bf16(af, bf, acc[f], 0, 0, 0);
    }
    __syncthreads();
  }
  int mbase = m0 + wave * 16 + (lane >> 4) * 4;
  int ncol0 = lane & 15;
#pragma unroll
  for (int f = 0; f < NFRAG; f++) {
    int n = f * 16 + ncol0;
#pragma unroll
    for (int r = 0; r < 4; r++) {
      int m = mbase + r;
      if (m < Mstore && n < Nstore) {
        int ch = CHAN_M ? m : n;
        float val = acc[f][r] * bns[ch] + (cb[ch] * bns[ch] + bnt[ch]);
        size_t o = (size_t)b * sCb + (size_t)m * ldc + n;
        if (F32OUT) ((float*)C)[o] = val;
        else ((u16*)C)[o] = f2bf(val);
      }
    }
  }
}

// ---------- v_local = BN(dwconv_s2(v4) + b) -> vlT (bf16 [b][49][512]) ----------
__global__ __launch_bounds__(256) void k_dwconv_v(const u16* __restrict__ v4, const float* __restrict__ w,
    const float* __restrict__ bias, const float* __restrict__ bns, const float* __restrict__ bnt,
    u16* __restrict__ vlt) {
  int b = blockIdx.y, ct = blockIdx.x;
  __shared__ u16 tile[64][196];
  int tid = threadIdx.x, wave = tid >> 6, lane = tid & 63;
  const u16* vbp = v4 + ((size_t)b * DH + ct * 64) * NPOS;
  for (int r = wave; r < 64; r += 4) {
    const u16* row = vbp + (size_t)r * NPOS;
    tile[r][lane]       = row[lane];
    tile[r][lane + 64]  = row[lane + 64];
    tile[r][lane + 128] = row[lane + 128];
    if (lane < 4) tile[r][lane + 192] = row[lane + 192];
  }
  __syncthreads();
  for (int idx = tid; idx < 64 * N2; idx += 256) {
    int cl = idx & 63, n2 = idx >> 6;
    int ch = ct * 64 + cl;
    int r = n2 / RES2, s = n2 % RES2;
    float acc = bias[ch];
#pragma unroll
    for (int dy = 0; dy < 3; dy++) {
      int ry = 2 * r - 1 + dy;
      if (ry < 0 || ry >= RES) continue;
#pragma unroll
      for (int dx = 0; dx < 3; dx++) {
        int sx = 2 * s - 1 + dx;
        if (sx < 0 || sx >= RES) continue;
        acc += w[ch * 9 + dy * 3 + dx] * bf2f(tile[cl][ry * RES + sx]);
      }
    }
    vlt[((size_t)b * N2 + n2) * DH + ch] = f2bf(acc * bns[ch] + bnt[ch]);
  }
}

// ---------- MFMA attention per (b,h): S=qk*scale+bias, softmax, PV; += v_local; gelu -> gT ----------
// LDS strides: P/V rows = 232 u16 = 464 B = 116 dw; 116 mod 32 = 20 -> 8 distinct
// 4-bank ranges over 16 rows -> 2-way aliasing (free). Rows 16B-aligned (464 = 29*16).
__global__ __launch_bounds__(256) void k_attn_mfma(const u16* __restrict__ qT, const u16* __restrict__ kT,
    const u16* __restrict__ v4, const float* __restrict__ biasx, const u16* __restrict__ vlT,
    u16* __restrict__ gT) {
  int h = blockIdx.x, b = blockIdx.y;
  __shared__ __align__(16) u16 q_lds[64 * 32];     //  4.0 KB  (K padded 16->32 w/ zeros)
  __shared__ __align__(16) u16 k_lds[208 * 32];    // 13.0 KB  (rows >=196 zero)
  __shared__ __align__(16) u16 p_lds[64 * 232];    // 29.0 KB  (cols 208..223 zero)
  __shared__ __align__(16) u16 v_lds[64 * 232];    // 29.0 KB  (cols 196..223 zero)
  int tid = threadIdx.x, w = tid >> 6, l = tid & 63;

  // --- stage q: row = tid>>2, part = tid&3 (parts 2,3 = K-pad zeros) ---
  {
    int row = tid >> 2, part = tid & 3;
    s16x8 val = (s16x8){0, 0, 0, 0, 0, 0, 0, 0};
    if (part < 2 && row < N2)
      val = *(const s16x8*)(qT + ((size_t)b * N2 + row) * NH_KD + h * 16 + part * 8);
    *(s16x8*)(&q_lds[row * 32 + part * 8]) = val;
  }
  // --- stage k ---
  for (int row = tid >> 2; row < 208; row += 64) {
    int part = tid & 3;
    s16x8 val = (s16x8){0, 0, 0, 0, 0, 0, 0, 0};
    if (part < 2 && row < NPOS)
      val = *(const s16x8*)(kT + ((size_t)b * NPOS + row) * NH_KD + h * 16 + part * 8);
    *(s16x8*)(&k_lds[row * 32 + part * 8]) = val;
  }
  // --- stage v: wave w rows w*16..w*16+15; dwords 0..97 copy, 98..111 zero ---
  for (int r = 0; r < 16; r++) {
    int row = w * 16 + r;
    const uint* gsrc = (const uint*)(v4 + ((size_t)b * DH + h * DHEAD + row) * NPOS);
    uint* dst = (uint*)&v_lds[row * 232];
    dst[l] = gsrc[l];
    int j = l + 64;
    uint vv = 0;
    if (j < 98) vv = gsrc[j];
    if (j < 112) dst[j] = vv;
  }
  // --- zero p_lds cols 208..223 (dwords 104..111) ---
  for (int idx = tid; idx < 64 * 8; idx += 256) {
    ((uint*)&p_lds[(idx >> 3) * 232])[104 + (idx & 7)] = 0;
  }
  __syncthreads();

  // --- QK^T: wave w owns rows w*16..w*16+15; 13 col-frags ---
  f32x4 s[13];
  {
    s16x8 af = *(const s16x8*)(&q_lds[(w * 16 + (l & 15)) * 32 + (l >> 4) * 8]);
#pragma unroll
    for (int f = 0; f < 13; f++) {
      s16x8 bf = *(const s16x8*)(&k_lds[(f * 16 + (l & 15)) * 32 + (l >> 4) * 8]);
      s[f] = __builtin_amdgcn_mfma_f32_16x16x32_bf16(af, bf, (f32x4){0.f, 0.f, 0.f, 0.f}, 0, 0, 0);
    }
  }
  // --- scale + bias + mask (C layout: col = l&15, row = (l>>4)*4 + reg) ---
  int mbase = w * 16 + (l >> 4) * 4;
  int ncol = l & 15;
  const float* bxp = biasx + (size_t)h * N2 * NPOS;
#pragma unroll
  for (int f = 0; f < 13; f++) {
    int n = f * 16 + ncol;
#pragma unroll
    for (int r = 0; r < 4; r++) {
      int m = mbase + r;
      s[f][r] = (m < N2 && n < NPOS) ? s[f][r] * SCALE_Q + bxp[m * NPOS + n] : -1e30f;
    }
  }
  // --- softmax: rows live in 16-lane groups -> shfl_xor 1,2,4,8 ---
#pragma unroll
  for (int r = 0; r < 4; r++) {
    float mx = s[0][r];
#pragma unroll
    for (int f = 1; f < 13; f++) mx = fmaxf(mx, s[f][r]);
    mx = fmaxf(mx, __shfl_xor(mx, 1)); mx = fmaxf(mx, __shfl_xor(mx, 2));
    mx = fmaxf(mx, __shfl_xor(mx, 4)); mx = fmaxf(mx, __shfl_xor(mx, 8));
    float sum = 0.f;
#pragma unroll
    for (int f = 0; f < 13; f++) { s[f][r] = __expf(s[f][r] - mx); sum += s[f][r]; }
    sum += __shfl_xor(sum, 1); sum += __shfl_xor(sum, 2);
    sum += __shfl_xor(sum, 4); sum += __shfl_xor(sum, 8);
    float inv = 1.f / sum;
#pragma unroll
    for (int f = 0; f < 13; f++) s[f][r] *= inv;
  }
  // --- P -> LDS (bf16), wave-local rows ---
#pragma unroll
  for (int f = 0; f < 13; f++) {
    int n = f * 16 + ncol;
#pragma unroll
    for (int r = 0; r < 4; r++)
      p_lds[(mbase + r) * 232 + n] = f2bf(s[f][r]);
  }
  __syncthreads();

  // --- PV: A = P rows (wave-local m-tile), B = V rows (d), K = 224 ---
  f32x4 o[4];
#pragma unroll
  for (int f = 0; f < 4; f++) o[f] = (f32x4){0.f, 0.f, 0.f, 0.f};
  for (int kk = 0; kk < 224; kk += 32) {
    s16x8 pa = *(const s16x8*)(&p_lds[(w * 16 + (l & 15)) * 232 + kk + (l >> 4) * 8]);
#pragma unroll
    for (int f = 0; f < 4; f++) {
      s16x8 vb = *(const s16x8*)(&v_lds[(f * 16 + (l & 15)) * 232 + kk + (l >> 4) * 8]);
      o[f] = __builtin_amdgcn_mfma_f32_16x16x32_bf16(pa, vb, o[f], 0, 0, 0);
    }
  }
  // --- epilogue: + v_local, gelu, store ---
#pragma unroll
  for (int f = 0; f < 4; f++) {
    int d = f * 16 + ncol;
#pragma unroll
    for (int r = 0; r < 4; r++) {
      int m = mbase + r;
      if (m < N2) {
        size_t oo = ((size_t)b * N2 + m) * DH + h * DHEAD + d;
        float xv = o[f][r] + bf2f(vlT[oo]);
        float g = 0.5f * xv * (1.f + erff(xv * 0.70710678118f));
        gT[oo] = f2bf(g);
      }
    }
  }
}

extern "C" void kernel_launch(void* const* d_in, const int* in_sizes, int n_in,
                              void* d_out, int out_size, void* d_ws, size_t ws_size,
                              hipStream_t stream) {
  const float* x   = (const float*)d_in[0];
  const float* qlw = (const float*)d_in[1];
  const float* qlb = (const float*)d_in[2];
  const float* qpw = (const float*)d_in[3];
  const float* qpb = (const float*)d_in[4];
  const float* qbs = (const float*)d_in[5];
  const float* qbt = (const float*)d_in[6];
  const float* kw  = (const float*)d_in[7];
  const float* kb  = (const float*)d_in[8];
  const float* kbs = (const float*)d_in[9];
  const float* kbt = (const float*)d_in[10];
  const float* vw  = (const float*)d_in[11];
  const float* vb  = (const float*)d_in[12];
  const float* vbs = (const float*)d_in[13];
  const float* vbt = (const float*)d_in[14];
  const float* vlw = (const float*)d_in[15];
  const float* vlb = (const float*)d_in[16];
  const float* vls = (const float*)d_in[17];
  const float* vlt_in = (const float*)d_in[18];
  const float* pw  = (const float*)d_in[19];
  const float* pb  = (const float*)d_in[20];
  const float* pbs = (const float*)d_in[21];
  const float* pbt = (const float*)d_in[22];
  const float* ab  = (const float*)d_in[23];
  const int*   bidx = (const int*)d_in[24];
  int noff = in_sizes[23] / NUM_HEADS;

  char* ws = (char*)d_ws;
  size_t off = 0;
  auto alloc = [&](size_t bytes) { char* p = ws + off; off += (bytes + 255) & ~(size_t)255; return p; };
  u16* xbT = (u16*)alloc((size_t)BATCH * NPOS * DIM * 2);      // 77.1 MB (aliased by gT later)
  u16* kTm = (u16*)alloc((size_t)BATCH * NPOS * NH_KD * 2);    // 25.7 MB
  u16* qlT = (u16*)alloc((size_t)BATCH * N2 * DIM * 2);        // 19.3 MB
  u16* qTm = (u16*)alloc((size_t)BATCH * N2 * NH_KD * 2);      //  6.4 MB
  u16* v4m = (u16*)alloc((size_t)BATCH * DH * NPOS * 2);       // 102.8 MB
  u16* vlTm = (u16*)alloc((size_t)BATCH * N2 * DH * 2);        // 25.7 MB
  float* bx = (float*)alloc((size_t)NUM_HEADS * N2 * NPOS * 4);
  u16* kwb = (u16*)alloc((size_t)NH_KD * DIM * 2);
  u16* vwb = (u16*)alloc((size_t)DH * DIM * 2);
  u16* qwb = (u16*)alloc((size_t)NH_KD * DIM * 2);
  u16* pwb = (u16*)alloc((size_t)OUT_DIM * DH * 2);
  u16* gTm = xbT;  // alias: all xbT readers complete before k_attn writes gT

  k_f2bf<<<(NH_KD * DIM + 255) / 256, 256, 0, stream>>>(kw, kwb, NH_KD * DIM);
  k_f2bf<<<(DH * DIM + 255) / 256, 256, 0, stream>>>(vw, vwb, DH * DIM);
  k_f2bf<<<(NH_KD * DIM + 255) / 256, 256, 0, stream>>>(qpw, qwb, NH_KD * DIM);
  k_f2bf<<<(OUT_DIM * DH + 255) / 256, 256, 0, stream>>>(pw, pwb, OUT_DIM * DH);
  k_biasx<<<(NUM_HEADS * N2 * NPOS + 255) / 256, 256, 0, stream>>>(ab, bidx, bx, noff);

  k_transpose<<<dim3(6, BATCH), 256, 0, stream>>>(x, xbT);
  k_dwconv_q<<<dim3((N2 * DIM + 255) / 256, BATCH), 256, 0, stream>>>(xbT, qlw, qlb, qlT);

  // k: C[b][n][o]  (m = n_spatial, ch = col)
  k_gemm_bt<8, false, false><<<dim3(4, BATCH), 256, 0, stream>>>(
      xbT, kwb, kTm, kb, kbs, kbt,
      (long)NPOS * DIM, 0, (long)NPOS * NH_KD, DIM, NPOS, NH_KD, NPOS, NH_KD, NH_KD);
  // v: C[b][o][n]  (m = channel)
  k_gemm_bt<13, true, false><<<dim3(8, BATCH), 256, 0, stream>>>(
      vwb, xbT, v4m, vb, vbs, vbt,
      0, (long)NPOS * DIM, (long)DH * NPOS, DIM, DH, NPOS, DH, NPOS, NPOS);
  // q: C[b][n2][o]
  k_gemm_bt<8, false, false><<<dim3(1, BATCH), 256, 0, stream>>>(
      qlT, qwb, qTm, qpb, qbs, qbt,
      (long)N2 * DIM, 0, (long)N2 * NH_KD, DIM, N2, NH_KD, N2, NH_KD, NH_KD);

  k_dwconv_v<<<dim3(8, BATCH), 256, 0, stream>>>(v4m, vlw, vlb, vls, vlt_in, vlTm);
  k_attn_mfma<<<dim3(NUM_HEADS, BATCH), 256, 0, stream>>>(qTm, kTm, v4m, bx, vlTm, gTm);

  // p: C[b][o][n2] -> d_out f32
  k_gemm_bt<4, true, true><<<dim3(12, BATCH), 256, 0, stream>>>(
      pwb, gTm, d_out, pb, pbs, pbt,
      0, (long)N2 * DH, (long)OUT_DIM * N2, DH, OUT_DIM, N2, OUT_DIM, N2, N2);
}

// Round 3
// 661.657 us; speedup vs baseline: 1.4908x; 1.1988x over previous
//
#include <hip/hip_runtime.h>
#include <math.h>

#define DIM 384
#define NUM_HEADS 8
#define RES 14
#define RES2 7
#define NPOS 196
#define N2 49
#define DHEAD 64
#define NH_KD 128
#define DH 512
#define OUT_DIM 768
#define BATCH 512
#define SCALE_Q 0.25f

typedef unsigned short u16;
typedef short s16x8 __attribute__((ext_vector_type(8)));
typedef short s16x4 __attribute__((ext_vector_type(4)));
typedef float f32x4 __attribute__((ext_vector_type(4)));
typedef unsigned int u32x2 __attribute__((ext_vector_type(2)));

__device__ __forceinline__ float bf2f(u16 u) {
  union { unsigned int i; float f; } v; v.i = ((unsigned int)u) << 16; return v.f;
}
__device__ __forceinline__ u16 f2bf(float f) {
  union { unsigned int i; float f; } v; v.f = f;
  unsigned int r = v.i + 0x7fffu + ((v.i >> 16) & 1u);
  return (u16)(r >> 16);
}

// ---------- small prep kernels ----------
__global__ __launch_bounds__(256) void k_f2bf(const float* __restrict__ s, u16* __restrict__ d, int n) {
  int i = blockIdx.x * 256 + threadIdx.x;
  if (i < n) d[i] = f2bf(s[i]);
}

// bias permuted to MFMA fragment order: bxp[h][m][ncol][16], entry f = bias(h, m, n=f*16+ncol), 0 if n>=196
__global__ __launch_bounds__(256) void k_biasx_p(const float* __restrict__ ab, const int* __restrict__ idxs,
                                                 float* __restrict__ bxp, int noff) {
  int i = blockIdx.x * 256 + threadIdx.x;
  if (i >= NUM_HEADS * N2 * 16 * 16) return;
  int f = i & 15, c = (i >> 4) & 15;
  int m = (i >> 8) % N2, h = i / (N2 * 256);
  int n = f * 16 + c;
  bxp[i] = (n < NPOS) ? ab[h * noff + idxs[m * NPOS + n]] : 0.f;
}

// ---------- x (f32 [b][384][196]) -> xbT (bf16 [b][196][384]) ----------
__global__ __launch_bounds__(256) void k_transpose(const float* __restrict__ x, u16* __restrict__ xt) {
  int b = blockIdx.y, c0 = blockIdx.x * 64;
  __shared__ u16 tile[64][196];
  int tid = threadIdx.x, wave = tid >> 6, lane = tid & 63;
  const float* xb = x + (size_t)b * DIM * NPOS;
  for (int r = wave; r < 64; r += 4) {
    const float* row = xb + (size_t)(c0 + r) * NPOS;
    tile[r][lane]       = f2bf(row[lane]);
    tile[r][lane + 64]  = f2bf(row[lane + 64]);
    tile[r][lane + 128] = f2bf(row[lane + 128]);
    if (lane < 4) tile[r][lane + 192] = f2bf(row[lane + 192]);
  }
  __syncthreads();
  u16* xtb = xt + (size_t)b * NPOS * DIM;
  for (int n = wave; n < NPOS; n += 4)
    xtb[(size_t)n * DIM + c0 + lane] = tile[lane][n];
}

// ---------- ql = dwconv_s2(x) + b + x[::2,::2]  -> qlT (bf16 [b][49][384]) ----------
__global__ __launch_bounds__(256) void k_dwconv_q(const u16* __restrict__ xt, const float* __restrict__ w,
                                                  const float* __restrict__ bias, u16* __restrict__ qlt) {
  int b = blockIdx.y;
  int lid = blockIdx.x * 256 + threadIdx.x;
  if (lid >= N2 * DIM) return;
  int n2 = lid / DIM, c = lid % DIM;
  int r = n2 / RES2, s = n2 % RES2;
  const u16* xb = xt + (size_t)b * NPOS * DIM;
  float acc = bias[c];
#pragma unroll
  for (int dy = 0; dy < 3; dy++) {
    int ry = 2 * r - 1 + dy;
    if (ry < 0 || ry >= RES) continue;
#pragma unroll
    for (int dx = 0; dx < 3; dx++) {
      int sx = 2 * s - 1 + dx;
      if (sx < 0 || sx >= RES) continue;
      acc += w[c * 9 + dy * 3 + dx] * bf2f(xb[(size_t)(ry * RES + sx) * DIM + c]);
    }
  }
  acc += bf2f(xb[(size_t)(2 * r * RES + 2 * s) * DIM + c]);  // strided residual
  qlt[((size_t)b * N2 + n2) * DIM + c] = f2bf(acc);
}

// ---------- generic  C[b][m][n] = (sum_k Arow[m][k]*Brow[n][k]) * s[ch] + (cb[ch]*s[ch]+t[ch]) ----------
template <int NFRAG, bool CHAN_M, bool F32OUT>
__global__ __launch_bounds__(256) void k_gemm_bt(
    const u16* __restrict__ A, const u16* __restrict__ B, void* __restrict__ C,
    const float* __restrict__ cb, const float* __restrict__ bns, const float* __restrict__ bnt,
    long sAb, long sBb, long sCb, int K, int Marows, int Brows, int Mstore, int Nstore, int ldc) {
  int b = blockIdx.y, m0 = blockIdx.x * 64;
  const u16* Ab = A + (size_t)b * sAb;
  const u16* Bb = B + (size_t)b * sBb;
  __shared__ __align__(16) u16 a_lds[64 * 32];
  __shared__ __align__(16) u16 b_lds[NFRAG * 16 * 32];
  int tid = threadIdx.x, wave = tid >> 6, lane = tid & 63;
  f32x4 acc[NFRAG];
#pragma unroll
  for (int f = 0; f < NFRAG; f++) acc[f] = (f32x4){0.f, 0.f, 0.f, 0.f};

  int arow_l = wave * 16 + (lane >> 2);
  int akoff = (lane & 3) * 8;
  int arow_g = m0 + arow_l; if (arow_g > Marows - 1) arow_g = Marows - 1;
  int brow0 = tid >> 2, bkoff = (tid & 3) * 8;
  int a_rd = (wave * 16 + (lane & 15)) * 32 + (lane >> 4) * 8;

  for (int kk = 0; kk < K; kk += 32) {
    *(s16x8*)(&a_lds[arow_l * 32 + akoff]) = *(const s16x8*)(Ab + (size_t)arow_g * K + kk + akoff);
#pragma unroll
    for (int i = 0; i < (NFRAG + 3) / 4; i++) {
      int rb = i * 64 + brow0;
      if (rb < Brows)
        *(s16x8*)(&b_lds[rb * 32 + bkoff]) = *(const s16x8*)(Bb + (size_t)rb * K + kk + bkoff);
    }
    __syncthreads();
    s16x8 af = *(const s16x8*)(&a_lds[a_rd]);
#pragma unroll
    for (int f = 0; f < NFRAG; f++) {
      s16x8 bf = *(const s16x8*)(&b_lds[(f * 16 + (lane & 15)) * 32 + (lane >> 4) * 8]);
      acc[f] = __builtin_amdgcn_mfma_f32_16x16x32_bf16(af, bf, acc[f], 0, 0, 0);
    }
    __syncthreads();
  }
  int mbase = m0 + wave * 16 + (lane >> 4) * 4;
  int ncol0 = lane & 15;
#pragma unroll
  for (int f = 0; f < NFRAG; f++) {
    int n = f * 16 + ncol0;
#pragma unroll
    for (int r = 0; r < 4; r++) {
      int m = mbase + r;
      if (m < Mstore && n < Nstore) {
        int ch = CHAN_M ? m : n;
        float val = acc[f][r] * bns[ch] + (cb[ch] * bns[ch] + bnt[ch]);
        size_t o = (size_t)b * sCb + (size_t)m * ldc + n;
        if (F32OUT) ((float*)C)[o] = val;
        else ((u16*)C)[o] = f2bf(val);
      }
    }
  }
}

// ---------- v_local = BN(dwconv_s2(v4) + b) -> vlT (bf16 [b][49][512]) ----------
__global__ __launch_bounds__(256) void k_dwconv_v(const u16* __restrict__ v4, const float* __restrict__ w,
    const float* __restrict__ bias, const float* __restrict__ bns, const float* __restrict__ bnt,
    u16* __restrict__ vlt) {
  int b = blockIdx.y, ct = blockIdx.x;
  __shared__ u16 tile[64][196];
  int tid = threadIdx.x, wave = tid >> 6, lane = tid & 63;
  const u16* vbp = v4 + ((size_t)b * DH + ct * 64) * NPOS;
  for (int r = wave; r < 64; r += 4) {
    const u16* row = vbp + (size_t)r * NPOS;
    tile[r][lane]       = row[lane];
    tile[r][lane + 64]  = row[lane + 64];
    tile[r][lane + 128] = row[lane + 128];
    if (lane < 4) tile[r][lane + 192] = row[lane + 192];
  }
  __syncthreads();
  for (int idx = tid; idx < 64 * N2; idx += 256) {
    int cl = idx & 63, n2 = idx >> 6;
    int ch = ct * 64 + cl;
    int r = n2 / RES2, s = n2 % RES2;
    float acc = bias[ch];
#pragma unroll
    for (int dy = 0; dy < 3; dy++) {
      int ry = 2 * r - 1 + dy;
      if (ry < 0 || ry >= RES) continue;
#pragma unroll
      for (int dx = 0; dx < 3; dx++) {
        int sx = 2 * s - 1 + dx;
        if (sx < 0 || sx >= RES) continue;
        acc += w[ch * 9 + dy * 3 + dx] * bf2f(tile[cl][ry * RES + sx]);
      }
    }
    vlt[((size_t)b * N2 + n2) * DH + ch] = f2bf(acc * bns[ch] + bnt[ch]);
  }
}

// ---------- MFMA attention per (b,h) ----------
// P/V LDS rows stride 232 u16 = 116 dw; 116 mod 32 = 20 -> 8 distinct bank classes -> 2-way (free).
// o_lds (f32, stride 68) overlaps the dead q/k region: 49*68*4 = 13.3 KB < 17.4 KB.
__global__ __launch_bounds__(256) void k_attn_mfma(const u16* __restrict__ qT, const u16* __restrict__ kT,
    const u16* __restrict__ v4, const float* __restrict__ bxp, const u16* __restrict__ vlT,
    u16* __restrict__ gT) {
  int h = blockIdx.x, b = blockIdx.y;
  __shared__ __align__(16) u16 smem[64 * 32 + 208 * 32 + 64 * 232 + 64 * 232];
  u16* q_lds = smem;                       // 64*32
  u16* k_lds = smem + 64 * 32;             // 208*32
  u16* p_lds = smem + 64 * 32 + 208 * 32;  // 64*232
  u16* v_lds = p_lds + 64 * 232;           // 64*232
  float* o_lds = (float*)smem;             // overlaps q_lds+k_lds
  int tid = threadIdx.x, w = tid >> 6, l = tid & 63;

  // --- stage q: row = tid>>2, part = tid&3 (parts 2,3 = K-pad zeros) ---
  {
    int row = tid >> 2, part = tid & 3;
    s16x8 val = (s16x8){0, 0, 0, 0, 0, 0, 0, 0};
    if (part < 2 && row < N2)
      val = *(const s16x8*)(qT + ((size_t)b * N2 + row) * NH_KD + h * 16 + part * 8);
    *(s16x8*)(&q_lds[row * 32 + part * 8]) = val;
  }
  // --- stage k ---
  for (int row = tid >> 2; row < 208; row += 64) {
    int part = tid & 3;
    s16x8 val = (s16x8){0, 0, 0, 0, 0, 0, 0, 0};
    if (part < 2 && row < NPOS)
      val = *(const s16x8*)(kT + ((size_t)b * NPOS + row) * NH_KD + h * 16 + part * 8);
    *(s16x8*)(&k_lds[row * 32 + part * 8]) = val;
  }
  // --- stage v: wave w rows w*16..w*16+15; one 8B load per lane per row (49*8B = full 392B row) ---
  for (int r = 0; r < 16; r++) {
    int row = w * 16 + r;
    const u32x2* gsrc = (const u32x2*)(v4 + ((size_t)b * DH + h * DHEAD + row) * NPOS);
    u32x2* dst = (u32x2*)&v_lds[row * 232];
    if (l < 49)       dst[l] = gsrc[l];
    else if (l < 56)  dst[49 + (l - 49)] = (u32x2){0, 0};   // dw 98..111 zero
  }
  // --- zero p_lds cols 208..223 (dwords 104..111) ---
  for (int idx = tid; idx < 64 * 8; idx += 256)
    ((uint*)&p_lds[(idx >> 3) * 232])[104 + (idx & 7)] = 0;

  // --- bias fragment loads (issued before barrier; independent of LDS) ---
  int mbase = w * 16 + (l >> 4) * 4;
  int ncol = l & 15;
  f32x4 bq[4][4];
#pragma unroll
  for (int r = 0; r < 4; r++) {
    int mm = mbase + r; if (mm > N2 - 1) mm = N2 - 1;
    const float* bb = bxp + (((size_t)h * N2 + mm) * 16 + ncol) * 16;
#pragma unroll
    for (int q = 0; q < 4; q++) bq[r][q] = *(const f32x4*)(bb + q * 4);
  }
  __syncthreads();

  // --- QK^T: wave w owns rows w*16..w*16+15; 13 col-frags ---
  f32x4 s[13];
  {
    s16x8 af = *(const s16x8*)(&q_lds[(w * 16 + (l & 15)) * 32 + (l >> 4) * 8]);
#pragma unroll
    for (int f = 0; f < 13; f++) {
      s16x8 bf = *(const s16x8*)(&k_lds[(f * 16 + (l & 15)) * 32 + (l >> 4) * 8]);
      s[f] = __builtin_amdgcn_mfma_f32_16x16x32_bf16(af, bf, (f32x4){0.f, 0.f, 0.f, 0.f}, 0, 0, 0);
    }
  }
  // --- scale + bias + mask (C layout: col = l&15, row = (l>>4)*4 + reg) ---
#pragma unroll
  for (int f = 0; f < 13; f++) {
    int n = f * 16 + ncol;
#pragma unroll
    for (int r = 0; r < 4; r++) {
      int m = mbase + r;
      s[f][r] = (m < N2 && n < NPOS) ? s[f][r] * SCALE_Q + bq[r][f >> 2][f & 3] : -1e30f;
    }
  }
  // --- softmax: rows live in 16-lane groups -> shfl_xor 1,2,4,8 ---
#pragma unroll
  for (int r = 0; r < 4; r++) {
    float mx = s[0][r];
#pragma unroll
    for (int f = 1; f < 13; f++) mx = fmaxf(mx, s[f][r]);
    mx = fmaxf(mx, __shfl_xor(mx, 1)); mx = fmaxf(mx, __shfl_xor(mx, 2));
    mx = fmaxf(mx, __shfl_xor(mx, 4)); mx = fmaxf(mx, __shfl_xor(mx, 8));
    float sum = 0.f;
#pragma unroll
    for (int f = 0; f < 13; f++) { s[f][r] = __expf(s[f][r] - mx); sum += s[f][r]; }
    sum += __shfl_xor(sum, 1); sum += __shfl_xor(sum, 2);
    sum += __shfl_xor(sum, 4); sum += __shfl_xor(sum, 8);
    float inv = 1.f / sum;
#pragma unroll
    for (int f = 0; f < 13; f++) s[f][r] *= inv;
  }
  // --- P -> LDS (bf16), wave-local rows ---
#pragma unroll
  for (int f = 0; f < 13; f++) {
    int n = f * 16 + ncol;
#pragma unroll
    for (int r = 0; r < 4; r++)
      p_lds[(mbase + r) * 232 + n] = f2bf(s[f][r]);
  }
  __syncthreads();

  // --- PV: A = P rows (wave-local m-tile), B = V rows (d), K = 224 ---
  f32x4 o[4];
#pragma unroll
  for (int f = 0; f < 4; f++) o[f] = (f32x4){0.f, 0.f, 0.f, 0.f};
  for (int kk = 0; kk < 224; kk += 32) {
    s16x8 pa = *(const s16x8*)(&p_lds[(w * 16 + (l & 15)) * 232 + kk + (l >> 4) * 8]);
#pragma unroll
    for (int f = 0; f < 4; f++) {
      s16x8 vb = *(const s16x8*)(&v_lds[(f * 16 + (l & 15)) * 232 + kk + (l >> 4) * 8]);
      o[f] = __builtin_amdgcn_mfma_f32_16x16x32_bf16(pa, vb, o[f], 0, 0, 0);
    }
  }
  // --- o -> o_lds (overlaps dead q/k region; q/k reads all completed before prior barrier) ---
#pragma unroll
  for (int f = 0; f < 4; f++)
#pragma unroll
    for (int r = 0; r < 4; r++) {
      int m = mbase + r;
      if (m < N2) o_lds[m * 68 + f * 16 + ncol] = o[f][r];
    }
  __syncthreads();

  // --- cooperative epilogue: coalesced vlT add + gelu + gT store ---
  for (int idx = tid; idx < N2 * 16; idx += 256) {
    int row = idx >> 4, c4 = (idx & 15) << 2;
    f32x4 ov = *(const f32x4*)(&o_lds[row * 68 + c4]);
    size_t go = ((size_t)b * N2 + row) * DH + h * DHEAD + c4;
    s16x4 vv = *(const s16x4*)(vlT + go);
    s16x4 outv;
#pragma unroll
    for (int e = 0; e < 4; e++) {
      float xv = ov[e] + bf2f((u16)vv[e]);
      float g = 0.5f * xv * (1.f + erff(xv * 0.70710678118f));
      outv[e] = (short)f2bf(g);
    }
    *(s16x4*)(gT + go) = outv;
  }
}

extern "C" void kernel_launch(void* const* d_in, const int* in_sizes, int n_in,
                              void* d_out, int out_size, void* d_ws, size_t ws_size,
                              hipStream_t stream) {
  const float* x   = (const float*)d_in[0];
  const float* qlw = (const float*)d_in[1];
  const float* qlb = (const float*)d_in[2];
  const float* qpw = (const float*)d_in[3];
  const float* qpb = (const float*)d_in[4];
  const float* qbs = (const float*)d_in[5];
  const float* qbt = (const float*)d_in[6];
  const float* kw  = (const float*)d_in[7];
  const float* kb  = (const float*)d_in[8];
  const float* kbs = (const float*)d_in[9];
  const float* kbt = (const float*)d_in[10];
  const float* vw  = (const float*)d_in[11];
  const float* vb  = (const float*)d_in[12];
  const float* vbs = (const float*)d_in[13];
  const float* vbt = (const float*)d_in[14];
  const float* vlw = (const float*)d_in[15];
  const float* vlb = (const float*)d_in[16];
  const float* vls = (const float*)d_in[17];
  const float* vlt_in = (const float*)d_in[18];
  const float* pw  = (const float*)d_in[19];
  const float* pb  = (const float*)d_in[20];
  const float* pbs = (const float*)d_in[21];
  const float* pbt = (const float*)d_in[22];
  const float* ab  = (const float*)d_in[23];
  const int*   bidx = (const int*)d_in[24];
  int noff = in_sizes[23] / NUM_HEADS;

  char* ws = (char*)d_ws;
  size_t off = 0;
  auto alloc = [&](size_t bytes) { char* p = ws + off; off += (bytes + 255) & ~(size_t)255; return p; };
  u16* xbT = (u16*)alloc((size_t)BATCH * NPOS * DIM * 2);      // 77.1 MB (aliased by gT later)
  u16* kTm = (u16*)alloc((size_t)BATCH * NPOS * NH_KD * 2);    // 25.7 MB
  u16* qlT = (u16*)alloc((size_t)BATCH * N2 * DIM * 2);        // 19.3 MB
  u16* qTm = (u16*)alloc((size_t)BATCH * N2 * NH_KD * 2);      //  6.4 MB
  u16* v4m = (u16*)alloc((size_t)BATCH * DH * NPOS * 2);       // 102.8 MB
  u16* vlTm = (u16*)alloc((size_t)BATCH * N2 * DH * 2);        // 25.7 MB
  float* bxp = (float*)alloc((size_t)NUM_HEADS * N2 * 16 * 16 * 4);  // 0.8 MB
  u16* kwb = (u16*)alloc((size_t)NH_KD * DIM * 2);
  u16* vwb = (u16*)alloc((size_t)DH * DIM * 2);
  u16* qwb = (u16*)alloc((size_t)NH_KD * DIM * 2);
  u16* pwb = (u16*)alloc((size_t)OUT_DIM * DH * 2);
  u16* gTm = xbT;  // alias: all xbT readers complete before k_attn writes gT

  k_f2bf<<<(NH_KD * DIM + 255) / 256, 256, 0, stream>>>(kw, kwb, NH_KD * DIM);
  k_f2bf<<<(DH * DIM + 255) / 256, 256, 0, stream>>>(vw, vwb, DH * DIM);
  k_f2bf<<<(NH_KD * DIM + 255) / 256, 256, 0, stream>>>(qpw, qwb, NH_KD * DIM);
  k_f2bf<<<(OUT_DIM * DH + 255) / 256, 256, 0, stream>>>(pw, pwb, OUT_DIM * DH);
  k_biasx_p<<<(NUM_HEADS * N2 * 16 * 16 + 255) / 256, 256, 0, stream>>>(ab, bidx, bxp, noff);

  k_transpose<<<dim3(6, BATCH), 256, 0, stream>>>(x, xbT);
  k_dwconv_q<<<dim3((N2 * DIM + 255) / 256, BATCH), 256, 0, stream>>>(xbT, qlw, qlb, qlT);

  // k: C[b][n][o]  (m = n_spatial, ch = col)
  k_gemm_bt<8, false, false><<<dim3(4, BATCH), 256, 0, stream>>>(
      xbT, kwb, kTm, kb, kbs, kbt,
      (long)NPOS * DIM, 0, (long)NPOS * NH_KD, DIM, NPOS, NH_KD, NPOS, NH_KD, NH_KD);
  // v: C[b][o][n]  (m = channel)
  k_gemm_bt<13, true, false><<<dim3(8, BATCH), 256, 0, stream>>>(
      vwb, xbT, v4m, vb, vbs, vbt,
      0, (long)NPOS * DIM, (long)DH * NPOS, DIM, DH, NPOS, DH, NPOS, NPOS);
  // q: C[b][n2][o]
  k_gemm_bt<8, false, false><<<dim3(1, BATCH), 256, 0, stream>>>(
      qlT, qwb, qTm, qpb, qbs, qbt,
      (long)N2 * DIM, 0, (long)N2 * NH_KD, DIM, N2, NH_KD, N2, NH_KD, NH_KD);

  k_dwconv_v<<<dim3(8, BATCH), 256, 0, stream>>>(v4m, vlw, vlb, vls, vlt_in, vlTm);
  k_attn_mfma<<<dim3(NUM_HEADS, BATCH), 256, 0, stream>>>(qTm, kTm, v4m, bxp, vlTm, gTm);

  // p: C[b][o][n2] -> d_out f32
  k_gemm_bt<4, true, true><<<dim3(12, BATCH), 256, 0, stream>>>(
      pwb, gTm, d_out, pb, pbs, pbt,
      0, (long)N2 * DH, (long)OUT_DIM * N2, DH, OUT_DIM, N2, OUT_DIM, N2, N2);
}